// Round 1
// baseline (1773.346 us; speedup 1.0000x reference)
//
#include <hip/hip_runtime.h>

// ---------------------------------------------------------------------------
// RoutingGNN: 2-layer GCN (sym-norm, self-loops) + linear head.
//   deg[v]  = 1 + #in-edges(v);  dis[v] = rsqrt(deg[v])
//   layer:  g[v] = (h @ W)[v] * dis[v]
//           out[v] = relu( dis[v] * (scatter_add(g[src]->dst)[v] + g[v]) + b )
//   head:   y[v] = h2[v] @ Wf + bf
// ---------------------------------------------------------------------------

__global__ void k_deg_init(float* __restrict__ deg, int n) {
    int i = blockIdx.x * blockDim.x + threadIdx.x;
    if (i < n) deg[i] = 1.0f;   // self-loop
}

__global__ void k_deg_edges(const int* __restrict__ dst, float* __restrict__ deg, int E) {
    int e = blockIdx.x * blockDim.x + threadIdx.x;
    if (e < E) atomicAdd(&deg[dst[e]], 1.0f);
}

__global__ void k_dis(float* __restrict__ deg, int n) {
    int i = blockIdx.x * blockDim.x + threadIdx.x;
    if (i < n) deg[i] = rsqrtf(deg[i]);   // deg >= 1 always
}

// g[v][f] = dis[v] * sum_k x[v][k] * W1[k][f]   (x: [n,8], W1: [8,32])
__global__ void k_gemm1(const float* __restrict__ x, const float* __restrict__ W1,
                        const float* __restrict__ dis, float* __restrict__ g, int n) {
    __shared__ float sW[256];
    int t = threadIdx.x;
    if (t < 256) sW[t] = W1[t];
    __syncthreads();
    int idx = blockIdx.x * 256 + t;
    int v = idx >> 5, f = idx & 31;
    if (v >= n) return;
    float s = 0.f;
#pragma unroll
    for (int k = 0; k < 8; ++k) s += x[v * 8 + k] * sW[k * 32 + f];
    g[idx] = s * dis[v];
}

// acc[dst] += g[src]; 8 threads per edge, float4 each (32 floats/row)
__global__ void k_scatter(const int* __restrict__ src, const int* __restrict__ dst,
                          const float4* __restrict__ g4, float* __restrict__ acc, int E) {
    int t = blockIdx.x * blockDim.x + threadIdx.x;
    if (t >= E * 8) return;
    int e = t >> 3, q = t & 7;
    int s = src[e], d = dst[e];
    float4 val = g4[(size_t)s * 8 + q];
    float* p = acc + (size_t)d * 32 + q * 4;
    atomicAdd(p + 0, val.x);
    atomicAdd(p + 1, val.y);
    atomicAdd(p + 2, val.z);
    atomicAdd(p + 3, val.w);
}

// h1[v][f] = relu(dis[v]*(acc[v][f] + g[v][f]) + b1[f]);
// g[v][f] <- dis[v] * sum_k h1[v][k] * W2[k][f]   (in-place over g)
__global__ void k_combine_gemm2(const float* __restrict__ W2, const float* __restrict__ b1,
                                const float* __restrict__ dis, const float* __restrict__ acc,
                                float* __restrict__ g, int n) {
    __shared__ float sW[1024];
    __shared__ float sh[8][32];
    int t = threadIdx.x;
    for (int i = t; i < 1024; i += 256) sW[i] = W2[i];
    int idx = blockIdx.x * 256 + t;
    int v = idx >> 5;
    int f = t & 31, row = t >> 5;
    float dv = 0.f, hp = 0.f;
    if (v < n) {
        dv = dis[v];
        hp = fmaxf(dv * (acc[idx] + g[idx]) + b1[f], 0.f);
    }
    sh[row][f] = hp;
    __syncthreads();
    if (v >= n) return;
    float s = 0.f;
#pragma unroll
    for (int k = 0; k < 32; ++k) s += sh[row][k] * sW[k * 32 + f];
    g[idx] = s * dv;
}

// h2[v][f] = relu(dis[v]*(acc[v][f] + g[v][f]) + b2[f]);  out[v] = h2[v].Wf + bf
__global__ void k_final(const float* __restrict__ Wf, const float* __restrict__ bf,
                        const float* __restrict__ b2, const float* __restrict__ dis,
                        const float* __restrict__ acc, const float* __restrict__ g,
                        float* __restrict__ out, int n) {
    __shared__ float sWf[32];
    int t = threadIdx.x;
    if (t < 32) sWf[t] = Wf[t];
    __syncthreads();
    int idx = blockIdx.x * 256 + t;
    int v = idx >> 5, f = t & 31;
    if (v >= n) return;
    float dv = dis[v];
    float hp = fmaxf(dv * (acc[idx] + g[idx]) + b2[f], 0.f);
    float s = hp * sWf[f];
#pragma unroll
    for (int off = 16; off; off >>= 1) s += __shfl_down(s, off, 32);
    if (f == 0) out[v] = s + bf[0];
}

extern "C" void kernel_launch(void* const* d_in, const int* in_sizes, int n_in,
                              void* d_out, int out_size, void* d_ws, size_t ws_size,
                              hipStream_t stream) {
    const float* x  = (const float*)d_in[0];
    const int*   ei = (const int*)d_in[1];   // [2, E] int32 (jax x64 disabled)
    const float* W1 = (const float*)d_in[2];
    const float* b1 = (const float*)d_in[3];
    const float* W2 = (const float*)d_in[4];
    const float* b2 = (const float*)d_in[5];
    const float* Wf = (const float*)d_in[6];
    const float* bf = (const float*)d_in[7];
    float* out = (float*)d_out;

    const int n = in_sizes[0] / 8;
    const int E = in_sizes[1] / 2;
    const int* src = ei;
    const int* dst = ei + E;

    float* dis = (float*)d_ws;                 // n floats
    float* g   = dis + n;                      // n*32 floats
    float* acc = g + (size_t)n * 32;           // n*32 floats

    const int B = 256;
    dim3 blk(B);

    // degree -> dis
    k_deg_init<<<dim3((n + B - 1) / B), blk, 0, stream>>>(dis, n);
    k_deg_edges<<<dim3((E + B - 1) / B), blk, 0, stream>>>(dst, dis, E);
    k_dis<<<dim3((n + B - 1) / B), blk, 0, stream>>>(dis, n);

    const int nf = n * 32;
    dim3 grid_nf((nf + B - 1) / B);
    dim3 grid_sc((E * 8 + B - 1) / B);

    // layer 1
    k_gemm1<<<grid_nf, blk, 0, stream>>>(x, W1, dis, g, n);
    hipMemsetAsync(acc, 0, (size_t)nf * sizeof(float), stream);
    k_scatter<<<grid_sc, blk, 0, stream>>>(src, dst, (const float4*)g, acc, E);

    // layer 2 (g updated in place)
    k_combine_gemm2<<<grid_nf, blk, 0, stream>>>(W2, b1, dis, acc, g, n);
    hipMemsetAsync(acc, 0, (size_t)nf * sizeof(float), stream);
    k_scatter<<<grid_sc, blk, 0, stream>>>(src, dst, (const float4*)g, acc, E);

    // head
    k_final<<<grid_nf, blk, 0, stream>>>(Wf, bf, b2, dis, acc, g, out, n);
}

// Round 2
// 395.322 us; speedup vs baseline: 4.4858x; 4.4858x over previous
//
#include <hip/hip_runtime.h>

// ---------------------------------------------------------------------------
// RoutingGNN: 2-layer GCN (sym-norm, self-loops) + linear head.
// Round 2: replace atomic scatter (2x806us, atomic-bound) with CSR build +
// gather. CSR: count -> block scan -> fill. Gather: 1 wave/node, 8 edges x
// 8 lanes x float4, shuffle-reduce, fused bias+ReLU combine.
// ---------------------------------------------------------------------------

__global__ void k_count(const int* __restrict__ dst, int* __restrict__ cnt, int E) {
    int e = blockIdx.x * blockDim.x + threadIdx.x;
    if (e < E) atomicAdd(&cnt[dst[e]], 1);
}

// per-256-block exclusive scan of cnt -> rowptr(partial); block total -> bsum;
// also dis = rsqrt(1 + cnt)
__global__ void k_scan_local(const int* __restrict__ cnt, int* __restrict__ rowptr,
                             int* __restrict__ bsum, float* __restrict__ dis, int n) {
    __shared__ int tmp[256];
    int t = threadIdx.x;
    int i = blockIdx.x * 256 + t;
    int v = (i < n) ? cnt[i] : 0;
    if (i < n) dis[i] = rsqrtf(1.0f + (float)v);
    tmp[t] = v;
    __syncthreads();
    for (int off = 1; off < 256; off <<= 1) {
        int add = (t >= off) ? tmp[t - off] : 0;
        __syncthreads();
        tmp[t] += add;
        __syncthreads();
    }
    if (i < n) rowptr[i] = tmp[t] - v;     // exclusive
    if (t == 255) bsum[blockIdx.x] = tmp[255];
}

// single block: exclusive scan of nb block sums (nb <= 1024)
__global__ void k_scan_bsum(int* __restrict__ bsum, int nb) {
    __shared__ int tmp[1024];
    int t = threadIdx.x;
    int v = (t < nb) ? bsum[t] : 0;
    tmp[t] = v;
    __syncthreads();
    for (int off = 1; off < 1024; off <<= 1) {
        int add = (t >= off) ? tmp[t - off] : 0;
        __syncthreads();
        tmp[t] += add;
        __syncthreads();
    }
    if (t < nb) bsum[t] = tmp[t] - v;
}

__global__ void k_scan_add(int* __restrict__ rowptr, int* __restrict__ wptr,
                           const int* __restrict__ bsum, int n, int E) {
    int i = blockIdx.x * 256 + threadIdx.x;
    if (i < n) {
        int r = rowptr[i] + bsum[i >> 8];
        rowptr[i] = r;
        wptr[i] = r;
    }
    if (i == 0) rowptr[n] = E;
}

__global__ void k_fill(const int* __restrict__ src, const int* __restrict__ dst,
                       int* __restrict__ wptr, int* __restrict__ col, int E) {
    int e = blockIdx.x * blockDim.x + threadIdx.x;
    if (e >= E) return;
    int pos = atomicAdd(&wptr[dst[e]], 1);
    col[pos] = src[e];
}

// g[v][f] = dis[v] * sum_k x[v][k] * W1[k][f]   (x: [n,8], W1: [8,32])
__global__ void k_gemm1(const float* __restrict__ x, const float* __restrict__ W1,
                        const float* __restrict__ dis, float* __restrict__ g, int n) {
    __shared__ float sW[256];
    int t = threadIdx.x;
    if (t < 256) sW[t] = W1[t];
    __syncthreads();
    int idx = blockIdx.x * 256 + t;
    int v = idx >> 5, f = idx & 31;
    if (v >= n) return;
    float s = 0.f;
#pragma unroll
    for (int k = 0; k < 8; ++k) s += x[v * 8 + k] * sW[k * 32 + f];
    g[idx] = s * dis[v];
}

// h[v] = relu( dis[v] * (sum_{u->v} g[u] + g[v]) + b )
// 1 wave per node: slot = lane>>3 walks edges, q = lane&7 is the float4 index.
__global__ void k_gather(const int* __restrict__ rowptr, const int* __restrict__ col,
                         const float4* __restrict__ g4, const float* __restrict__ dis,
                         const float* __restrict__ b, float4* __restrict__ h4, int n) {
    int t = threadIdx.x;
    int lane = t & 63;
    int slot = lane >> 3;
    int q = lane & 7;
    int v = blockIdx.x * 4 + (t >> 6);
    if (v >= n) return;
    int r0 = rowptr[v], r1 = rowptr[v + 1];
    float4 s = make_float4(0.f, 0.f, 0.f, 0.f);
    for (int i = r0 + slot; i < r1; i += 8) {
        int c = col[i];
        float4 gv = g4[(size_t)c * 8 + q];
        s.x += gv.x; s.y += gv.y; s.z += gv.z; s.w += gv.w;
    }
#pragma unroll
    for (int m = 8; m < 64; m <<= 1) {
        s.x += __shfl_xor(s.x, m, 64);
        s.y += __shfl_xor(s.y, m, 64);
        s.z += __shfl_xor(s.z, m, 64);
        s.w += __shfl_xor(s.w, m, 64);
    }
    if (slot == 0) {
        float dv = dis[v];
        float4 gv = g4[(size_t)v * 8 + q];   // self-loop
        float4 bv = ((const float4*)b)[q];
        float4 o;
        o.x = fmaxf(dv * (s.x + gv.x) + bv.x, 0.f);
        o.y = fmaxf(dv * (s.y + gv.y) + bv.y, 0.f);
        o.z = fmaxf(dv * (s.z + gv.z) + bv.z, 0.f);
        o.w = fmaxf(dv * (s.w + gv.w) + bv.w, 0.f);
        h4[(size_t)v * 8 + q] = o;
    }
}

// g[v][f] = dis[v] * sum_k h[v][k] * W2[k][f]
__global__ void k_gemm2(const float* __restrict__ W2, const float* __restrict__ dis,
                        const float* __restrict__ h, float* __restrict__ g, int n) {
    __shared__ float sW[1024];
    __shared__ float sh[8][32];
    int t = threadIdx.x;
    for (int i = t; i < 1024; i += 256) sW[i] = W2[i];
    int idx = blockIdx.x * 256 + t;
    int v = idx >> 5;
    int f = t & 31, row = t >> 5;
    float hv = (v < n * 1) ? h[idx] : 0.f;
    sh[row][f] = hv;
    __syncthreads();
    if (v >= n) return;
    float s = 0.f;
#pragma unroll
    for (int k = 0; k < 32; ++k) s += sh[row][k] * sW[k * 32 + f];
    g[idx] = s * dis[v];
}

// out[v] = h[v] . Wf + bf
__global__ void k_final(const float* __restrict__ Wf, const float* __restrict__ bf,
                        const float* __restrict__ h, float* __restrict__ out, int n) {
    __shared__ float sWf[32];
    int t = threadIdx.x;
    if (t < 32) sWf[t] = Wf[t];
    __syncthreads();
    int idx = blockIdx.x * 256 + t;
    int v = idx >> 5, f = t & 31;
    if (v >= n) return;
    float s = h[idx] * sWf[f];
#pragma unroll
    for (int off = 16; off; off >>= 1) s += __shfl_down(s, off, 32);
    if (f == 0) out[v] = s + bf[0];
}

extern "C" void kernel_launch(void* const* d_in, const int* in_sizes, int n_in,
                              void* d_out, int out_size, void* d_ws, size_t ws_size,
                              hipStream_t stream) {
    const float* x  = (const float*)d_in[0];
    const int*   ei = (const int*)d_in[1];   // [2, E] int32
    const float* W1 = (const float*)d_in[2];
    const float* b1 = (const float*)d_in[3];
    const float* W2 = (const float*)d_in[4];
    const float* b2 = (const float*)d_in[5];
    const float* Wf = (const float*)d_in[6];
    const float* bf = (const float*)d_in[7];
    float* out = (float*)d_out;

    const int n = in_sizes[0] / 8;
    const int E = in_sizes[1] / 2;
    const int* src = ei;
    const int* dst = ei + E;

    // workspace layout (~34.8 MB)
    float* dis   = (float*)d_ws;               // n
    float* g     = dis + n;                    // 32n (16B-aligned: n*4 % 16 == 0)
    float* h     = g + (size_t)n * 32;         // 32n
    int* rowptr  = (int*)(h + (size_t)n * 32); // n+1
    int* wptr    = rowptr + (n + 1);           // n  (doubles as cnt)
    int* col     = wptr + n;                   // E
    int* bsum    = col + E;                    // NB

    const int B = 256;
    const int NB = (n + B - 1) / B;
    dim3 blk(B);

    // --- CSR build + dis ---
    hipMemsetAsync(wptr, 0, (size_t)n * sizeof(int), stream);
    k_count<<<dim3((E + B - 1) / B), blk, 0, stream>>>(dst, wptr, E);
    k_scan_local<<<dim3(NB), blk, 0, stream>>>(wptr, rowptr, bsum, dis, n);
    k_scan_bsum<<<dim3(1), dim3(1024), 0, stream>>>(bsum, NB);
    k_scan_add<<<dim3(NB), blk, 0, stream>>>(rowptr, wptr, bsum, n, E);
    k_fill<<<dim3((E + B - 1) / B), blk, 0, stream>>>(src, dst, wptr, col, E);

    const int nf = n * 32;
    dim3 grid_nf((nf + B - 1) / B);
    dim3 grid_gv((n + 3) / 4);

    // --- layer 1 ---
    k_gemm1<<<grid_nf, blk, 0, stream>>>(x, W1, dis, g, n);
    k_gather<<<grid_gv, blk, 0, stream>>>(rowptr, col, (const float4*)g, dis, b1, (float4*)h, n);

    // --- layer 2 ---
    k_gemm2<<<grid_nf, blk, 0, stream>>>(W2, dis, h, g, n);
    k_gather<<<grid_gv, blk, 0, stream>>>(rowptr, col, (const float4*)g, dis, b2, (float4*)h, n);

    // --- head ---
    k_final<<<grid_nf, blk, 0, stream>>>(Wf, bf, h, out, n);
}

// Round 3
// 330.614 us; speedup vs baseline: 5.3638x; 1.1957x over previous
//
#include <hip/hip_runtime.h>

// ---------------------------------------------------------------------------
// RoutingGNN: 2-layer GCN (sym-norm, self-loops) + linear head.
// Round 3: kill k_fill's scattered-write cost (128MB WRITE_SIZE -> ~25MB) via
// dst-bucket binning (MSB radix pass) before CSR fill; aggregate 8-dim xs
// (not 32-dim g) for layer 1; fuse gather+GEMM1 and gather+head.
// ---------------------------------------------------------------------------

#define CHUNK 2048

// counts per-node indegree AND per-bucket sizes in one pass over dst
__global__ void k_count_hist(const int* __restrict__ dst, int* __restrict__ cnt,
                             int* __restrict__ bcnt, int E, int shift) {
    __shared__ int hist[256];
    int t = threadIdx.x;
    hist[t] = 0;
    __syncthreads();
    for (int e = blockIdx.x * 256 + t; e < E; e += gridDim.x * 256) {
        int d = dst[e];
        atomicAdd(&cnt[d], 1);
        atomicAdd(&hist[d >> shift], 1);
    }
    __syncthreads();
    if (hist[t]) atomicAdd(&bcnt[t], hist[t]);
}

// single block: exclusive scan of 256 bucket counts -> bbase, bcur
__global__ void k_bscan(const int* __restrict__ bcnt, int* __restrict__ bbase,
                        int* __restrict__ bcur) {
    __shared__ int tmp[256];
    int t = threadIdx.x;
    int v = bcnt[t];
    tmp[t] = v;
    __syncthreads();
    for (int off = 1; off < 256; off <<= 1) {
        int add = (t >= off) ? tmp[t - off] : 0;
        __syncthreads();
        tmp[t] += add;
        __syncthreads();
    }
    int excl = tmp[t] - v;
    bbase[t] = excl;
    bcur[t] = excl;
    if (t == 255) bbase[256] = tmp[255];
}

// per-256-block exclusive scan of cnt -> rowptr(partial); block total -> bsum;
// also dis = rsqrt(1 + cnt)
__global__ void k_scan_local(const int* __restrict__ cnt, int* __restrict__ rowptr,
                             int* __restrict__ bsum, float* __restrict__ dis, int n) {
    __shared__ int tmp[256];
    int t = threadIdx.x;
    int i = blockIdx.x * 256 + t;
    int v = (i < n) ? cnt[i] : 0;
    if (i < n) dis[i] = rsqrtf(1.0f + (float)v);
    tmp[t] = v;
    __syncthreads();
    for (int off = 1; off < 256; off <<= 1) {
        int add = (t >= off) ? tmp[t - off] : 0;
        __syncthreads();
        tmp[t] += add;
        __syncthreads();
    }
    if (i < n) rowptr[i] = tmp[t] - v;
    if (t == 255) bsum[blockIdx.x] = tmp[255];
}

__global__ void k_scan_bsum(int* __restrict__ bsum, int nb) {
    __shared__ int tmp[1024];
    int t = threadIdx.x;
    int v = (t < nb) ? bsum[t] : 0;
    tmp[t] = v;
    __syncthreads();
    for (int off = 1; off < 1024; off <<= 1) {
        int add = (t >= off) ? tmp[t - off] : 0;
        __syncthreads();
        tmp[t] += add;
        __syncthreads();
    }
    if (t < nb) bsum[t] = tmp[t] - v;
}

__global__ void k_scan_add(int* __restrict__ rowptr, int* __restrict__ wptr,
                           const int* __restrict__ bsum, int n, int E) {
    int i = blockIdx.x * 256 + threadIdx.x;
    if (i < n) {
        int r = rowptr[i] + bsum[i >> 8];
        rowptr[i] = r;
        wptr[i] = r;
    }
    if (i == 0) rowptr[n] = E;
}

// bin edges by dst-bucket into packed words (src<<shift | dst&mask)
__global__ void k_binA(const int* __restrict__ src, const int* __restrict__ dst,
                       int* __restrict__ bcur, int* __restrict__ bpair, int E, int shift) {
    __shared__ int hist[256];
    __shared__ int base[256];
    int t = threadIdx.x;
    hist[t] = 0;
    __syncthreads();
    int s0 = blockIdx.x * CHUNK;
    int pk[8], bu[8], rk[8];
    int mask = (1 << shift) - 1;
#pragma unroll
    for (int k = 0; k < 8; ++k) {
        int e = s0 + k * 256 + t;
        if (e < E) {
            int s = src[e], d = dst[e];
            int b = d >> shift;
            bu[k] = b;
            pk[k] = (s << shift) | (d & mask);
            rk[k] = atomicAdd(&hist[b], 1);
        } else bu[k] = -1;
    }
    __syncthreads();
    if (hist[t] > 0) base[t] = atomicAdd(&bcur[t], hist[t]);
    __syncthreads();
#pragma unroll
    for (int k = 0; k < 8; ++k)
        if (bu[k] >= 0) bpair[base[bu[k]] + rk[k]] = pk[k];
}

// fill CSR col from bucket-ordered edges; writes stay in small L2 windows
__global__ void k_fillB(const int* __restrict__ bpair, const int* __restrict__ bbase,
                        int* __restrict__ wptr, int* __restrict__ col, int shift) {
    int b = blockIdx.x >> 3, sub = blockIdx.x & 7;
    int start = bbase[b], end = bbase[b + 1];
    int len = end - start;
    int c0 = start + ((len * sub) >> 3);
    int c1 = start + ((len * (sub + 1)) >> 3);
    int mask = (1 << shift) - 1;
    int dbase = b << shift;
    for (int i = c0 + threadIdx.x; i < c1; i += 256) {
        int p = bpair[i];
        int d = dbase + (p & mask);
        int s = p >> shift;
        int pos = atomicAdd(&wptr[d], 1);
        col[pos] = s;
    }
}

// xs[v][k] = dis[v] * x[v][k]   (8 floats per node)
__global__ void k_prep_xs(const float* __restrict__ x, const float* __restrict__ dis,
                          float* __restrict__ xs, int n8) {
    int i = blockIdx.x * 256 + threadIdx.x;
    if (i < n8) xs[i] = x[i] * dis[i >> 3];
}

// layer 1 fused: agg8 = sum_{u->v} xs[u]; t = agg8 + xs[v];
// h[v][f] = relu(dis[v] * (t @ W1)[f] + b1[f])
__global__ void k_g1(const int* __restrict__ rowptr, const int* __restrict__ col,
                     const float* __restrict__ xs, const float* __restrict__ dis,
                     const float* __restrict__ W1, const float* __restrict__ b1,
                     float* __restrict__ h, int n) {
    __shared__ float sW[256];
    int t = threadIdx.x;
    sW[t] = W1[t];
    __syncthreads();
    int v = blockIdx.x * 4 + (t >> 6);
    if (v >= n) return;
    int lane = t & 63, slot = lane >> 3, q = lane & 7;
    int r0 = rowptr[v], r1 = rowptr[v + 1];
    float s = 0.f;
    for (int i = r0 + slot; i < r1; i += 8) {
        int c = col[i];
        s += xs[(size_t)c * 8 + q];
    }
    s += __shfl_xor(s, 8, 64);
    s += __shfl_xor(s, 16, 64);
    s += __shfl_xor(s, 32, 64);
    s += xs[(size_t)v * 8 + q];   // self-loop term
    float tq[8];
#pragma unroll
    for (int j = 0; j < 8; ++j) tq[j] = __shfl(s, j, 64);
    if (lane < 32) {
        float dv = dis[v];
        float acc = 0.f;
#pragma unroll
        for (int j = 0; j < 8; ++j) acc += tq[j] * sW[j * 32 + lane];
        h[(size_t)v * 32 + lane] = fmaxf(dv * acc + b1[lane], 0.f);
    }
}

// g2[v][f] = dis[v] * sum_k h[v][k] * W2[k][f]   (in-place over h)
__global__ void k_gemm2(const float* __restrict__ W2, const float* __restrict__ dis,
                        float* __restrict__ h, int n) {
    __shared__ float sW[1024];
    __shared__ float sh[8][32];
    int t = threadIdx.x;
    for (int i = t; i < 1024; i += 256) sW[i] = W2[i];
    int idx = blockIdx.x * 256 + t;
    int v = idx >> 5, f = t & 31, row = t >> 5;
    sh[row][f] = (v < n) ? h[idx] : 0.f;
    __syncthreads();
    if (v >= n) return;
    float s = 0.f;
#pragma unroll
    for (int k = 0; k < 32; ++k) s += sh[row][k] * sW[k * 32 + f];
    h[idx] = s * dis[v];
}

// layer 2 + head fused: S = sum_{u->v} g2[u]; h2 = relu(dis*(S+g2[v])+b2);
// out[v] = h2 . Wf + bf
__global__ void k_g2f(const int* __restrict__ rowptr, const int* __restrict__ col,
                      const float4* __restrict__ g4, const float* __restrict__ dis,
                      const float* __restrict__ b2, const float* __restrict__ Wf,
                      const float* __restrict__ bf, float* __restrict__ out, int n) {
    int t = threadIdx.x;
    int v = blockIdx.x * 4 + (t >> 6);
    if (v >= n) return;
    int lane = t & 63, slot = lane >> 3, q = lane & 7;
    int r0 = rowptr[v], r1 = rowptr[v + 1];
    float4 s = make_float4(0.f, 0.f, 0.f, 0.f);
    for (int i = r0 + slot; i < r1; i += 8) {
        int c = col[i];
        float4 gv = g4[(size_t)c * 8 + q];
        s.x += gv.x; s.y += gv.y; s.z += gv.z; s.w += gv.w;
    }
#pragma unroll
    for (int m = 8; m < 64; m <<= 1) {
        s.x += __shfl_xor(s.x, m, 64);
        s.y += __shfl_xor(s.y, m, 64);
        s.z += __shfl_xor(s.z, m, 64);
        s.w += __shfl_xor(s.w, m, 64);
    }
    float4 gv = g4[(size_t)v * 8 + q];     // self-loop
    float4 bv = ((const float4*)b2)[q];
    float4 wv = ((const float4*)Wf)[q];
    float dv = dis[v];
    float p = fmaxf(dv * (s.x + gv.x) + bv.x, 0.f) * wv.x
            + fmaxf(dv * (s.y + gv.y) + bv.y, 0.f) * wv.y
            + fmaxf(dv * (s.z + gv.z) + bv.z, 0.f) * wv.z
            + fmaxf(dv * (s.w + gv.w) + bv.w, 0.f) * wv.w;
    p += __shfl_xor(p, 1, 64);
    p += __shfl_xor(p, 2, 64);
    p += __shfl_xor(p, 4, 64);
    if (lane == 0) out[v] = p + bf[0];
}

extern "C" void kernel_launch(void* const* d_in, const int* in_sizes, int n_in,
                              void* d_out, int out_size, void* d_ws, size_t ws_size,
                              hipStream_t stream) {
    const float* x  = (const float*)d_in[0];
    const int*   ei = (const int*)d_in[1];   // [2, E] int32
    const float* W1 = (const float*)d_in[2];
    const float* b1 = (const float*)d_in[3];
    const float* W2 = (const float*)d_in[4];
    const float* b2 = (const float*)d_in[5];
    const float* Wf = (const float*)d_in[6];
    const float* bf = (const float*)d_in[7];
    float* out = (float*)d_out;

    const int n = in_sizes[0] / 8;
    const int E = in_sizes[1] / 2;
    const int* src = ei;
    const int* dst = ei + E;

    int shift = 0;
    while (((n - 1) >> shift) >= 256) ++shift;   // n=100k -> 9 (196 buckets)

    const int B = 256;
    const int NB = (n + B - 1) / B;

    // workspace layout (~32.5 MB)
    float* dis   = (float*)d_ws;                // n
    float* xs    = dis + n;                     // 8n
    float* h     = xs + (size_t)n * 8;          // 32n (h1, then g2 in-place)
    int* rowptr  = (int*)(h + (size_t)n * 32);  // n+1
    int* wptr    = rowptr + (n + 1);            // n   (cnt, then fill cursor)
    int* bcnt    = wptr + n;                    // 256
    int* bbase   = bcnt + 256;                  // 257
    int* bcur    = bbase + 257;                 // 256
    int* bsum    = bcur + 256;                  // NB
    int* col     = bsum + NB;                   // E
    int* bpair   = col + E;                     // E

    dim3 blk(B);

    // --- CSR build ---
    hipMemsetAsync(wptr, 0, (size_t)(n + 256) * sizeof(int), stream);  // wptr + bcnt
    k_count_hist<<<dim3(1024), blk, 0, stream>>>(dst, wptr, bcnt, E, shift);
    k_bscan<<<dim3(1), blk, 0, stream>>>(bcnt, bbase, bcur);
    k_scan_local<<<dim3(NB), blk, 0, stream>>>(wptr, rowptr, bsum, dis, n);
    k_scan_bsum<<<dim3(1), dim3(1024), 0, stream>>>(bsum, NB);
    k_scan_add<<<dim3(NB), blk, 0, stream>>>(rowptr, wptr, bsum, n, E);
    k_binA<<<dim3((E + CHUNK - 1) / CHUNK), blk, 0, stream>>>(src, dst, bcur, bpair, E, shift);
    k_fillB<<<dim3(256 * 8), blk, 0, stream>>>(bpair, bbase, wptr, col, shift);

    // --- layer 1 (8-dim aggregation, fused GEMM1) ---
    k_prep_xs<<<dim3((n * 8 + B - 1) / B), blk, 0, stream>>>(x, dis, xs, n * 8);
    k_g1<<<dim3((n + 3) / 4), blk, 0, stream>>>(rowptr, col, xs, dis, W1, b1, h, n);

    // --- layer 2 + head ---
    k_gemm2<<<dim3((n * 32 + B - 1) / B), blk, 0, stream>>>(W2, dis, h, n);
    k_g2f<<<dim3((n + 3) / 4), blk, 0, stream>>>(rowptr, col, (const float4*)h, dis,
                                                 b2, Wf, bf, out, n);
}

// Round 4
// 241.792 us; speedup vs baseline: 7.3342x; 1.3674x over previous
//
#include <hip/hip_runtime.h>

// ---------------------------------------------------------------------------
// RoutingGNN: 2-layer GCN (sym-norm, self-loops) + linear head.
// Round 4: kill k_count_hist's 2M global atomics (100us). CSR build is now:
//   k_bhist  - bucket histogram of dst (LDS atomics only)
//   k_bscan  - exclusive scan of <=512 bucket counts
//   k_binA   - bin edges into bucket-ordered packed words
//   k_fill2  - one block per bucket: LDS counting sort -> cnt/dis/rowptr/col
// No global atomics anywhere in the build; node-level scan eliminated
// (rowptr[v] = bbase[bucket] + in-bucket exclusive count).
// ---------------------------------------------------------------------------

#define CHUNK 2048
#define SHIFT 8          // 256 nodes per bucket; n <= 131072 -> <= 512 buckets
#define BMASK 255

// per-bucket edge counts (LDS histogram, flush once per block)
__global__ void k_bhist(const int4* __restrict__ dst4, int* __restrict__ bcnt, int E4) {
    __shared__ int hist[512];
    int t = threadIdx.x;
    hist[t] = 0; hist[t + 256] = 0;
    __syncthreads();
    int stride = gridDim.x * 256;
    for (int i = blockIdx.x * 256 + t; i < E4; i += stride) {
        int4 d = dst4[i];
        atomicAdd(&hist[d.x >> SHIFT], 1);
        atomicAdd(&hist[d.y >> SHIFT], 1);
        atomicAdd(&hist[d.z >> SHIFT], 1);
        atomicAdd(&hist[d.w >> SHIFT], 1);
    }
    __syncthreads();
    if (hist[t]) atomicAdd(&bcnt[t], hist[t]);
    if (hist[t + 256]) atomicAdd(&bcnt[t + 256], hist[t + 256]);
}

// single block, 512 threads: exclusive scan of bucket counts -> bbase, bcur
__global__ void k_bscan(const int* __restrict__ bcnt, int* __restrict__ bbase,
                        int* __restrict__ bcur, int nbuck, int* __restrict__ rowptr,
                        int n, int E) {
    __shared__ int tmp[512];
    int t = threadIdx.x;
    int v = (t < nbuck) ? bcnt[t] : 0;
    tmp[t] = v;
    __syncthreads();
    for (int off = 1; off < 512; off <<= 1) {
        int add = (t >= off) ? tmp[t - off] : 0;
        __syncthreads();
        tmp[t] += add;
        __syncthreads();
    }
    if (t < nbuck) {
        int excl = tmp[t] - v;
        bbase[t] = excl;
        bcur[t] = excl;
    }
    if (t == 0) { bbase[nbuck] = E; rowptr[n] = E; }
}

// bin edges by dst-bucket into packed words (src<<SHIFT | dst&BMASK)
__global__ void k_binA(const int* __restrict__ src, const int* __restrict__ dst,
                       int* __restrict__ bcur, int* __restrict__ bpair, int E) {
    __shared__ int hist[512];
    __shared__ int base[512];
    int t = threadIdx.x;
    hist[t] = 0; hist[t + 256] = 0;
    __syncthreads();
    int s0 = blockIdx.x * CHUNK;
    int pk[8], bu[8], rk[8];
#pragma unroll
    for (int k = 0; k < 8; ++k) {
        int e = s0 + k * 256 + t;
        if (e < E) {
            int s = src[e], d = dst[e];
            int b = d >> SHIFT;
            bu[k] = b;
            pk[k] = (s << SHIFT) | (d & BMASK);
            rk[k] = atomicAdd(&hist[b], 1);
        } else bu[k] = -1;
    }
    __syncthreads();
    if (hist[t] > 0) base[t] = atomicAdd(&bcur[t], hist[t]);
    if (hist[t + 256] > 0) base[t + 256] = atomicAdd(&bcur[t + 256], hist[t + 256]);
    __syncthreads();
#pragma unroll
    for (int k = 0; k < 8; ++k)
        if (bu[k] >= 0) bpair[base[bu[k]] + rk[k]] = pk[k];
}

// one block (512 thr) per bucket: LDS counting sort.
// pass1: histogram local dst; scan -> rowptr/dis/cursors; pass2: place col.
__global__ void k_fill2(const int* __restrict__ bpair, const int* __restrict__ bbase,
                        int* __restrict__ rowptr, float* __restrict__ dis,
                        int* __restrict__ col, int n) {
    __shared__ int cnt[256];
    __shared__ int tmp[256];
    __shared__ int cur[256];
    int b = blockIdx.x;
    int t = threadIdx.x;
    int start = bbase[b], end = bbase[b + 1];
    if (t < 256) cnt[t] = 0;
    __syncthreads();
    for (int i = start + t; i < end; i += 512)
        atomicAdd(&cnt[bpair[i] & BMASK], 1);
    __syncthreads();
    int v0 = (t < 256) ? cnt[t] : 0;
    if (t < 256) tmp[t] = v0;
    __syncthreads();
    for (int off = 1; off < 256; off <<= 1) {
        int add = (t < 256 && t >= off) ? tmp[t - off] : 0;
        __syncthreads();
        if (t < 256) tmp[t] += add;
        __syncthreads();
    }
    if (t < 256) {
        int v = (b << SHIFT) + t;
        if (v < n) {
            int r = start + tmp[t] - v0;   // exclusive
            rowptr[v] = r;
            cur[t] = r;
            dis[v] = rsqrtf(1.0f + (float)v0);
        }
    }
    __syncthreads();
    for (int i = start + t; i < end; i += 512) {
        int p = bpair[i];
        int pos = atomicAdd(&cur[p & BMASK], 1);
        col[pos] = p >> SHIFT;
    }
}

// xs[v][k] = dis[v] * x[v][k]
__global__ void k_prep_xs(const float* __restrict__ x, const float* __restrict__ dis,
                          float* __restrict__ xs, int n8) {
    int i = blockIdx.x * 256 + threadIdx.x;
    if (i < n8) xs[i] = x[i] * dis[i >> 3];
}

// layer 1 fused: agg8 = sum_{u->v} xs[u] (+ xs[v]);
// h[v][f] = relu(dis[v] * (agg8 @ W1)[f] + b1[f])
__global__ void k_g1(const int* __restrict__ rowptr, const int* __restrict__ col,
                     const float* __restrict__ xs, const float* __restrict__ dis,
                     const float* __restrict__ W1, const float* __restrict__ b1,
                     float* __restrict__ h, int n) {
    __shared__ float sW[256];
    int t = threadIdx.x;
    sW[t] = W1[t];
    __syncthreads();
    int v = blockIdx.x * 4 + (t >> 6);
    if (v >= n) return;
    int lane = t & 63, slot = lane >> 3, q = lane & 7;
    int r0 = rowptr[v], r1 = rowptr[v + 1];
    float s = 0.f;
    for (int i = r0 + slot; i < r1; i += 8) {
        int c = col[i];
        s += xs[(size_t)c * 8 + q];
    }
    s += __shfl_xor(s, 8, 64);
    s += __shfl_xor(s, 16, 64);
    s += __shfl_xor(s, 32, 64);
    s += xs[(size_t)v * 8 + q];   // self-loop
    float tq[8];
#pragma unroll
    for (int j = 0; j < 8; ++j) tq[j] = __shfl(s, j, 64);
    if (lane < 32) {
        float dv = dis[v];
        float acc = 0.f;
#pragma unroll
        for (int j = 0; j < 8; ++j) acc += tq[j] * sW[j * 32 + lane];
        h[(size_t)v * 32 + lane] = fmaxf(dv * acc + b1[lane], 0.f);
    }
}

// g2[v][f] = dis[v] * sum_k h[v][k] * W2[k][f]   (in-place over h)
__global__ void k_gemm2(const float* __restrict__ W2, const float* __restrict__ dis,
                        float* __restrict__ h, int n) {
    __shared__ float sW[1024];
    __shared__ float sh[8][32];
    int t = threadIdx.x;
    for (int i = t; i < 1024; i += 256) sW[i] = W2[i];
    int idx = blockIdx.x * 256 + t;
    int v = idx >> 5, f = t & 31, row = t >> 5;
    sh[row][f] = (v < n) ? h[idx] : 0.f;
    __syncthreads();
    if (v >= n) return;
    float s = 0.f;
#pragma unroll
    for (int k = 0; k < 32; ++k) s += sh[row][k] * sW[k * 32 + f];
    h[idx] = s * dis[v];
}

// layer 2 + head fused
__global__ void k_g2f(const int* __restrict__ rowptr, const int* __restrict__ col,
                      const float4* __restrict__ g4, const float* __restrict__ dis,
                      const float* __restrict__ b2, const float* __restrict__ Wf,
                      const float* __restrict__ bf, float* __restrict__ out, int n) {
    int t = threadIdx.x;
    int v = blockIdx.x * 4 + (t >> 6);
    if (v >= n) return;
    int lane = t & 63, slot = lane >> 3, q = lane & 7;
    int r0 = rowptr[v], r1 = rowptr[v + 1];
    float4 s = make_float4(0.f, 0.f, 0.f, 0.f);
    for (int i = r0 + slot; i < r1; i += 8) {
        int c = col[i];
        float4 gv = g4[(size_t)c * 8 + q];
        s.x += gv.x; s.y += gv.y; s.z += gv.z; s.w += gv.w;
    }
#pragma unroll
    for (int m = 8; m < 64; m <<= 1) {
        s.x += __shfl_xor(s.x, m, 64);
        s.y += __shfl_xor(s.y, m, 64);
        s.z += __shfl_xor(s.z, m, 64);
        s.w += __shfl_xor(s.w, m, 64);
    }
    float4 gv = g4[(size_t)v * 8 + q];
    float4 bv = ((const float4*)b2)[q];
    float4 wv = ((const float4*)Wf)[q];
    float dv = dis[v];
    float p = fmaxf(dv * (s.x + gv.x) + bv.x, 0.f) * wv.x
            + fmaxf(dv * (s.y + gv.y) + bv.y, 0.f) * wv.y
            + fmaxf(dv * (s.z + gv.z) + bv.z, 0.f) * wv.z
            + fmaxf(dv * (s.w + gv.w) + bv.w, 0.f) * wv.w;
    p += __shfl_xor(p, 1, 64);
    p += __shfl_xor(p, 2, 64);
    p += __shfl_xor(p, 4, 64);
    if (lane == 0) out[v] = p + bf[0];
}

extern "C" void kernel_launch(void* const* d_in, const int* in_sizes, int n_in,
                              void* d_out, int out_size, void* d_ws, size_t ws_size,
                              hipStream_t stream) {
    const float* x  = (const float*)d_in[0];
    const int*   ei = (const int*)d_in[1];   // [2, E] int32
    const float* W1 = (const float*)d_in[2];
    const float* b1 = (const float*)d_in[3];
    const float* W2 = (const float*)d_in[4];
    const float* b2 = (const float*)d_in[5];
    const float* Wf = (const float*)d_in[6];
    const float* bf = (const float*)d_in[7];
    float* out = (float*)d_out;

    const int n = in_sizes[0] / 8;
    const int E = in_sizes[1] / 2;
    const int* src = ei;
    const int* dst = ei + E;
    const int nbuck = (n + 255) >> 8;        // n=100k -> 391 (<= 512)

    // workspace (~33 MB)
    float* dis   = (float*)d_ws;                // n
    float* xs    = dis + n;                     // 8n
    float* h     = xs + (size_t)n * 8;          // 32n
    int* rowptr  = (int*)(h + (size_t)n * 32);  // n+1
    int* bcnt    = rowptr + (n + 1);            // 512
    int* bbase   = bcnt + 512;                  // 513
    int* bcur    = bbase + 513;                 // 512
    int* col     = bcur + 512;                  // E
    int* bpair   = col + E;                     // E

    const int B = 256;
    dim3 blk(B);

    // --- CSR build (no global atomics) ---
    hipMemsetAsync(bcnt, 0, 512 * sizeof(int), stream);
    k_bhist<<<dim3(2048), blk, 0, stream>>>((const int4*)dst, bcnt, E >> 2);
    k_bscan<<<dim3(1), dim3(512), 0, stream>>>(bcnt, bbase, bcur, nbuck, rowptr, n, E);
    k_binA<<<dim3((E + CHUNK - 1) / CHUNK), blk, 0, stream>>>(src, dst, bcur, bpair, E);
    k_fill2<<<dim3(nbuck), dim3(512), 0, stream>>>(bpair, bbase, rowptr, dis, col, n);

    // --- layer 1 ---
    k_prep_xs<<<dim3((n * 8 + B - 1) / B), blk, 0, stream>>>(x, dis, xs, n * 8);
    k_g1<<<dim3((n + 3) / 4), blk, 0, stream>>>(rowptr, col, xs, dis, W1, b1, h, n);

    // --- layer 2 + head ---
    k_gemm2<<<dim3((n * 32 + B - 1) / B), blk, 0, stream>>>(W2, dis, h, n);
    k_g2f<<<dim3((n + 3) / 4), blk, 0, stream>>>(rowptr, col, (const float4*)h, dis,
                                                 b2, Wf, bf, out, n);
}

// Round 5
// 186.055 us; speedup vs baseline: 9.5313x; 1.2996x over previous
//
#include <hip/hip_runtime.h>

// ---------------------------------------------------------------------------
// RoutingGNN: 2-layer GCN (sym-norm, self-loops) + linear head.
// Round 5: zero-global-atomic CSR build (radix-sort structure):
//   k_hist  - per-block private bucket histograms -> partials (no atomics)
//   k_scan2 - partials -> per-(block,bucket) exclusive offsets + bucket bases
//   k_binA2 - bin edges via block-private LDS cursors -> bucket-ordered bpair
//   k_fill2 - per-bucket LDS counting sort -> rowptr/dis/col (+ fused xs)
// Fusions: prep_xs into fill2; gemm2 into g1 (shuffle matvec, h never hits mem).
// ---------------------------------------------------------------------------

#define NBLK 256
#define SHIFT 8          // 256 nodes/bucket; n <= 131072 -> <= 512 buckets
#define BMASK 255

// per-block bucket histogram -> part[b][512]  (no global atomics)
__global__ void k_hist(const int* __restrict__ dst, int* __restrict__ part, int E) {
    __shared__ int hist[512];
    int t = threadIdx.x;           // 256
    hist[t] = 0; hist[t + 256] = 0;
    __syncthreads();
    int E4 = E >> 2;
    int chunk4 = (E4 + NBLK - 1) / NBLK;
    int b = blockIdx.x;
    int s4 = b * chunk4;
    int e4 = min(s4 + chunk4, E4);
    const int4* dst4 = (const int4*)dst;
    for (int i = s4 + t; i < e4; i += 256) {
        int4 d = dst4[i];
        atomicAdd(&hist[d.x >> SHIFT], 1);
        atomicAdd(&hist[d.y >> SHIFT], 1);
        atomicAdd(&hist[d.z >> SHIFT], 1);
        atomicAdd(&hist[d.w >> SHIFT], 1);
    }
    if (b == NBLK - 1) {
        for (int e = (E4 << 2) + t; e < E; e += 256)
            atomicAdd(&hist[dst[e] >> SHIFT], 1);
    }
    __syncthreads();
    part[b * 512 + t] = hist[t];
    part[b * 512 + 256 + t] = hist[t + 256];
}

// single block, 512 thr: column-walk partials -> per-block exclusive offsets;
// LDS scan of column totals -> bbase (exclusive bucket bases)
__global__ void k_scan2(int* __restrict__ part, int* __restrict__ bbase,
                        int* __restrict__ rowptr, int n, int E) {
    __shared__ int tmp[512];
    int t = threadIdx.x;
    int run = 0;
    for (int b = 0; b < NBLK; b += 4) {
        int i0 = (b + 0) * 512 + t, i1 = (b + 1) * 512 + t;
        int i2 = (b + 2) * 512 + t, i3 = (b + 3) * 512 + t;
        int c0 = part[i0], c1 = part[i1], c2 = part[i2], c3 = part[i3];
        part[i0] = run; run += c0;
        part[i1] = run; run += c1;
        part[i2] = run; run += c2;
        part[i3] = run; run += c3;
    }
    tmp[t] = run;
    __syncthreads();
    int v = run;
    for (int off = 1; off < 512; off <<= 1) {
        int add = (t >= off) ? tmp[t - off] : 0;
        __syncthreads();
        tmp[t] += add;
        __syncthreads();
    }
    bbase[t] = tmp[t] - v;
    if (t == 511) bbase[512] = tmp[511];
    if (t == 0) rowptr[n] = E;
}

// bin edges into bucket-ordered packed words via block-private LDS cursors
__global__ void k_binA2(const int* __restrict__ src, const int* __restrict__ dst,
                        const int* __restrict__ part, const int* __restrict__ bbase,
                        int* __restrict__ bpair, int E) {
    __shared__ int cur[512];
    int t = threadIdx.x;           // 512
    int b = blockIdx.x;
    cur[t] = part[b * 512 + t] + bbase[t];
    __syncthreads();
    int E4 = E >> 2;
    int chunk4 = (E4 + NBLK - 1) / NBLK;
    int s4 = b * chunk4;
    int e4 = min(s4 + chunk4, E4);
    const int4* src4 = (const int4*)src;
    const int4* dst4 = (const int4*)dst;
    for (int i = s4 + t; i < e4; i += 512) {
        int4 s = src4[i];
        int4 d = dst4[i];
        int p0 = atomicAdd(&cur[d.x >> SHIFT], 1);
        bpair[p0] = (s.x << SHIFT) | (d.x & BMASK);
        int p1 = atomicAdd(&cur[d.y >> SHIFT], 1);
        bpair[p1] = (s.y << SHIFT) | (d.y & BMASK);
        int p2 = atomicAdd(&cur[d.z >> SHIFT], 1);
        bpair[p2] = (s.z << SHIFT) | (d.z & BMASK);
        int p3 = atomicAdd(&cur[d.w >> SHIFT], 1);
        bpair[p3] = (s.w << SHIFT) | (d.w & BMASK);
    }
    if (b == NBLK - 1) {
        for (int e = (E4 << 2) + t; e < E; e += 512) {
            int sv = src[e], dv = dst[e];
            int p = atomicAdd(&cur[dv >> SHIFT], 1);
            bpair[p] = (sv << SHIFT) | (dv & BMASK);
        }
    }
}

// one block (512 thr) per bucket: LDS counting sort -> rowptr/dis/col; fused xs
__global__ void k_fill2(const int* __restrict__ bpair, const int* __restrict__ bbase,
                        const float* __restrict__ x,
                        int* __restrict__ rowptr, float* __restrict__ dis,
                        float* __restrict__ xs, int* __restrict__ col, int n) {
    __shared__ int cnt[256];
    __shared__ int tmp[256];
    __shared__ int cur[256];
    __shared__ float sdis[256];
    int b = blockIdx.x;
    int t = threadIdx.x;           // 512
    int start = bbase[b], end = bbase[b + 1];
    if (t < 256) cnt[t] = 0;
    __syncthreads();
    for (int i = start + t; i < end; i += 512)
        atomicAdd(&cnt[bpair[i] & BMASK], 1);
    __syncthreads();
    int v0 = (t < 256) ? cnt[t] : 0;
    if (t < 256) tmp[t] = v0;
    __syncthreads();
    for (int off = 1; off < 256; off <<= 1) {
        int add = (t < 256 && t >= off) ? tmp[t - off] : 0;
        __syncthreads();
        if (t < 256) tmp[t] += add;
        __syncthreads();
    }
    if (t < 256) {
        int v = (b << SHIFT) + t;
        if (v < n) {
            int r = start + tmp[t] - v0;
            rowptr[v] = r;
            cur[t] = r;
            float dv = rsqrtf(1.0f + (float)v0);
            dis[v] = dv;
            sdis[t] = dv;
        }
    }
    __syncthreads();
    int gbase = (b << SHIFT) * 8;
    int n8 = n * 8;
    for (int i = t; i < 2048; i += 512) {
        int gi = gbase + i;
        if (gi < n8) xs[gi] = x[gi] * sdis[i >> 3];
    }
    for (int i = start + t; i < end; i += 512) {
        int p = bpair[i];
        int pos = atomicAdd(&cur[p & BMASK], 1);
        col[pos] = p >> SHIFT;
    }
}

// layer 1 fully fused: agg8(+self) -> @W1 +b1 -> relu -> @W2 (shuffle) -> *dis
__global__ void k_g1f(const int* __restrict__ rowptr, const int* __restrict__ col,
                      const float* __restrict__ xs, const float* __restrict__ dis,
                      const float* __restrict__ W1, const float* __restrict__ b1,
                      const float* __restrict__ W2, float* __restrict__ g, int n) {
    __shared__ float sW1[256];
    __shared__ float sW2[1024];
    int t = threadIdx.x;
    sW1[t] = W1[t];
    for (int i = t; i < 1024; i += 256) sW2[i] = W2[i];
    __syncthreads();
    int v = blockIdx.x * 4 + (t >> 6);
    if (v >= n) return;
    int lane = t & 63, slot = lane >> 3, q = lane & 7;
    int r0 = rowptr[v], r1 = rowptr[v + 1];
    float s = 0.f;
    for (int i = r0 + slot; i < r1; i += 8)
        s += xs[(size_t)col[i] * 8 + q];
    s += __shfl_xor(s, 8, 64);
    s += __shfl_xor(s, 16, 64);
    s += __shfl_xor(s, 32, 64);
    s += xs[(size_t)v * 8 + q];    // self-loop
    float tq[8];
#pragma unroll
    for (int j = 0; j < 8; ++j) tq[j] = __shfl(s, j, 64);
    int f = lane & 31;
    float dv = dis[v];
    float acc = 0.f;
#pragma unroll
    for (int j = 0; j < 8; ++j) acc += tq[j] * sW1[j * 32 + f];
    float hp = fmaxf(dv * acc + b1[f], 0.f);
    float g2 = 0.f;
#pragma unroll
    for (int k = 0; k < 32; ++k) g2 += __shfl(hp, k, 64) * sW2[k * 32 + f];
    if (lane < 32) g[(size_t)v * 32 + f] = g2 * dv;
}

// layer 2 + head fused
__global__ void k_g2f(const int* __restrict__ rowptr, const int* __restrict__ col,
                      const float4* __restrict__ g4, const float* __restrict__ dis,
                      const float* __restrict__ b2, const float* __restrict__ Wf,
                      const float* __restrict__ bf, float* __restrict__ out, int n) {
    int t = threadIdx.x;
    int v = blockIdx.x * 4 + (t >> 6);
    if (v >= n) return;
    int lane = t & 63, slot = lane >> 3, q = lane & 7;
    int r0 = rowptr[v], r1 = rowptr[v + 1];
    float4 s = make_float4(0.f, 0.f, 0.f, 0.f);
    for (int i = r0 + slot; i < r1; i += 8) {
        float4 gv = g4[(size_t)col[i] * 8 + q];
        s.x += gv.x; s.y += gv.y; s.z += gv.z; s.w += gv.w;
    }
#pragma unroll
    for (int m = 8; m < 64; m <<= 1) {
        s.x += __shfl_xor(s.x, m, 64);
        s.y += __shfl_xor(s.y, m, 64);
        s.z += __shfl_xor(s.z, m, 64);
        s.w += __shfl_xor(s.w, m, 64);
    }
    float4 gv = g4[(size_t)v * 8 + q];
    float4 bv = ((const float4*)b2)[q];
    float4 wv = ((const float4*)Wf)[q];
    float dv = dis[v];
    float p = fmaxf(dv * (s.x + gv.x) + bv.x, 0.f) * wv.x
            + fmaxf(dv * (s.y + gv.y) + bv.y, 0.f) * wv.y
            + fmaxf(dv * (s.z + gv.z) + bv.z, 0.f) * wv.z
            + fmaxf(dv * (s.w + gv.w) + bv.w, 0.f) * wv.w;
    p += __shfl_xor(p, 1, 64);
    p += __shfl_xor(p, 2, 64);
    p += __shfl_xor(p, 4, 64);
    if (lane == 0) out[v] = p + bf[0];
}

extern "C" void kernel_launch(void* const* d_in, const int* in_sizes, int n_in,
                              void* d_out, int out_size, void* d_ws, size_t ws_size,
                              hipStream_t stream) {
    const float* x  = (const float*)d_in[0];
    const int*   ei = (const int*)d_in[1];   // [2, E] int32
    const float* W1 = (const float*)d_in[2];
    const float* b1 = (const float*)d_in[3];
    const float* W2 = (const float*)d_in[4];
    const float* b2 = (const float*)d_in[5];
    const float* Wf = (const float*)d_in[6];
    const float* bf = (const float*)d_in[7];
    float* out = (float*)d_out;

    const int n = in_sizes[0] / 8;
    const int E = in_sizes[1] / 2;
    const int* src = ei;
    const int* dst = ei + E;
    const int nbuck = (n + 255) >> 8;        // n=100k -> 391

    // workspace (~33.4 MB)
    float* dis   = (float*)d_ws;                // n
    float* xs    = dis + n;                     // 8n
    float* g     = xs + (size_t)n * 8;          // 32n
    int* rowptr  = (int*)(g + (size_t)n * 32);  // n+1
    int* bbase   = rowptr + (n + 1);            // 513
    int* part    = bbase + 513;                 // NBLK*512
    int* col     = part + NBLK * 512;           // E
    int* bpair   = col + E;                     // E

    // --- CSR build (zero global atomics) ---
    k_hist <<<dim3(NBLK), dim3(256), 0, stream>>>(dst, part, E);
    k_scan2<<<dim3(1),    dim3(512), 0, stream>>>(part, bbase, rowptr, n, E);
    k_binA2<<<dim3(NBLK), dim3(512), 0, stream>>>(src, dst, part, bbase, bpair, E);
    k_fill2<<<dim3(nbuck),dim3(512), 0, stream>>>(bpair, bbase, x, rowptr, dis, xs, col, n);

    // --- layer 1 (gather8 + W1 + relu + W2, fused) ---
    k_g1f<<<dim3((n + 3) / 4), dim3(256), 0, stream>>>(rowptr, col, xs, dis, W1, b1, W2, g, n);

    // --- layer 2 + head ---
    k_g2f<<<dim3((n + 3) / 4), dim3(256), 0, stream>>>(rowptr, col, (const float4*)g, dis,
                                                       b2, Wf, bf, out, n);
}

// Round 6
// 163.905 us; speedup vs baseline: 10.8194x; 1.1351x over previous
//
#include <hip/hip_runtime.h>

// ---------------------------------------------------------------------------
// RoutingGNN: 2-layer GCN (sym-norm, self-loops) + linear head.
// Round 6: de-fuse the W2 matvec from k_g1 (round-5's 32x ds_bpermute shuffle
// matvec cost ~40us, far more than the 25.6MB h round-trip it saved).
//   CSR build (zero global atomics): k_hist -> k_scan2 -> k_binA2 -> k_fill2
//   k_g1    : gather8(xs) + W1 + bias + relu -> h
//   k_gemm2 : h -> dis * (h @ W2), in-place, LDS-staged (padded vs bank confl)
//   k_g2f   : gather32 + combine + bias + relu + Wf head -> out
// ---------------------------------------------------------------------------

#define NBLK 256
#define SHIFT 8          // 256 nodes/bucket; n <= 131072 -> <= 512 buckets
#define BMASK 255

// per-block bucket histogram -> part[b][512]  (no global atomics)
__global__ void k_hist(const int* __restrict__ dst, int* __restrict__ part, int E) {
    __shared__ int hist[512];
    int t = threadIdx.x;           // 256
    hist[t] = 0; hist[t + 256] = 0;
    __syncthreads();
    int E4 = E >> 2;
    int chunk4 = (E4 + NBLK - 1) / NBLK;
    int b = blockIdx.x;
    int s4 = b * chunk4;
    int e4 = min(s4 + chunk4, E4);
    const int4* dst4 = (const int4*)dst;
    for (int i = s4 + t; i < e4; i += 256) {
        int4 d = dst4[i];
        atomicAdd(&hist[d.x >> SHIFT], 1);
        atomicAdd(&hist[d.y >> SHIFT], 1);
        atomicAdd(&hist[d.z >> SHIFT], 1);
        atomicAdd(&hist[d.w >> SHIFT], 1);
    }
    if (b == NBLK - 1) {
        for (int e = (E4 << 2) + t; e < E; e += 256)
            atomicAdd(&hist[dst[e] >> SHIFT], 1);
    }
    __syncthreads();
    part[b * 512 + t] = hist[t];
    part[b * 512 + 256 + t] = hist[t + 256];
}

// single block, 512 thr: column-walk partials -> per-block exclusive offsets;
// LDS scan of column totals -> bbase (exclusive bucket bases)
__global__ void k_scan2(int* __restrict__ part, int* __restrict__ bbase,
                        int* __restrict__ rowptr, int n, int E) {
    __shared__ int tmp[512];
    int t = threadIdx.x;
    int run = 0;
    for (int b = 0; b < NBLK; b += 4) {
        int i0 = (b + 0) * 512 + t, i1 = (b + 1) * 512 + t;
        int i2 = (b + 2) * 512 + t, i3 = (b + 3) * 512 + t;
        int c0 = part[i0], c1 = part[i1], c2 = part[i2], c3 = part[i3];
        part[i0] = run; run += c0;
        part[i1] = run; run += c1;
        part[i2] = run; run += c2;
        part[i3] = run; run += c3;
    }
    tmp[t] = run;
    __syncthreads();
    int v = run;
    for (int off = 1; off < 512; off <<= 1) {
        int add = (t >= off) ? tmp[t - off] : 0;
        __syncthreads();
        tmp[t] += add;
        __syncthreads();
    }
    bbase[t] = tmp[t] - v;
    if (t == 511) bbase[512] = tmp[511];
    if (t == 0) rowptr[n] = E;
}

// bin edges into bucket-ordered packed words via block-private LDS cursors
__global__ void k_binA2(const int* __restrict__ src, const int* __restrict__ dst,
                        const int* __restrict__ part, const int* __restrict__ bbase,
                        int* __restrict__ bpair, int E) {
    __shared__ int cur[512];
    int t = threadIdx.x;           // 512
    int b = blockIdx.x;
    cur[t] = part[b * 512 + t] + bbase[t];
    __syncthreads();
    int E4 = E >> 2;
    int chunk4 = (E4 + NBLK - 1) / NBLK;
    int s4 = b * chunk4;
    int e4 = min(s4 + chunk4, E4);
    const int4* src4 = (const int4*)src;
    const int4* dst4 = (const int4*)dst;
    for (int i = s4 + t; i < e4; i += 512) {
        int4 s = src4[i];
        int4 d = dst4[i];
        int p0 = atomicAdd(&cur[d.x >> SHIFT], 1);
        bpair[p0] = (s.x << SHIFT) | (d.x & BMASK);
        int p1 = atomicAdd(&cur[d.y >> SHIFT], 1);
        bpair[p1] = (s.y << SHIFT) | (d.y & BMASK);
        int p2 = atomicAdd(&cur[d.z >> SHIFT], 1);
        bpair[p2] = (s.z << SHIFT) | (d.z & BMASK);
        int p3 = atomicAdd(&cur[d.w >> SHIFT], 1);
        bpair[p3] = (s.w << SHIFT) | (d.w & BMASK);
    }
    if (b == NBLK - 1) {
        for (int e = (E4 << 2) + t; e < E; e += 512) {
            int sv = src[e], dv = dst[e];
            int p = atomicAdd(&cur[dv >> SHIFT], 1);
            bpair[p] = (sv << SHIFT) | (dv & BMASK);
        }
    }
}

// one block (512 thr) per bucket: LDS counting sort -> rowptr/dis/col; fused xs
__global__ void k_fill2(const int* __restrict__ bpair, const int* __restrict__ bbase,
                        const float* __restrict__ x,
                        int* __restrict__ rowptr, float* __restrict__ dis,
                        float* __restrict__ xs, int* __restrict__ col, int n) {
    __shared__ int cnt[256];
    __shared__ int tmp[256];
    __shared__ int cur[256];
    __shared__ float sdis[256];
    int b = blockIdx.x;
    int t = threadIdx.x;           // 512
    int start = bbase[b], end = bbase[b + 1];
    if (t < 256) cnt[t] = 0;
    __syncthreads();
    for (int i = start + t; i < end; i += 512)
        atomicAdd(&cnt[bpair[i] & BMASK], 1);
    __syncthreads();
    int v0 = (t < 256) ? cnt[t] : 0;
    if (t < 256) tmp[t] = v0;
    __syncthreads();
    for (int off = 1; off < 256; off <<= 1) {
        int add = (t < 256 && t >= off) ? tmp[t - off] : 0;
        __syncthreads();
        if (t < 256) tmp[t] += add;
        __syncthreads();
    }
    if (t < 256) {
        int v = (b << SHIFT) + t;
        if (v < n) {
            int r = start + tmp[t] - v0;
            rowptr[v] = r;
            cur[t] = r;
            float dv = rsqrtf(1.0f + (float)v0);
            dis[v] = dv;
            sdis[t] = dv;
        }
    }
    __syncthreads();
    int gbase = (b << SHIFT) * 8;
    int n8 = n * 8;
    for (int i = t; i < 2048; i += 512) {
        int gi = gbase + i;
        if (gi < n8) xs[gi] = x[gi] * sdis[i >> 3];
    }
    for (int i = start + t; i < end; i += 512) {
        int p = bpair[i];
        int pos = atomicAdd(&cur[p & BMASK], 1);
        col[pos] = p >> SHIFT;
    }
}

// layer 1: agg8 = sum_{u->v} xs[u] (+ xs[v]);
// h[v][f] = relu(dis[v] * (agg8 @ W1)[f] + b1[f])
__global__ void k_g1(const int* __restrict__ rowptr, const int* __restrict__ col,
                     const float* __restrict__ xs, const float* __restrict__ dis,
                     const float* __restrict__ W1, const float* __restrict__ b1,
                     float* __restrict__ h, int n) {
    __shared__ float sW[256];
    int t = threadIdx.x;
    sW[t] = W1[t];
    __syncthreads();
    int v = blockIdx.x * 4 + (t >> 6);
    if (v >= n) return;
    int lane = t & 63, slot = lane >> 3, q = lane & 7;
    int r0 = rowptr[v], r1 = rowptr[v + 1];
    float s = 0.f;
    for (int i = r0 + slot; i < r1; i += 8)
        s += xs[(size_t)col[i] * 8 + q];
    s += __shfl_xor(s, 8, 64);
    s += __shfl_xor(s, 16, 64);
    s += __shfl_xor(s, 32, 64);
    s += xs[(size_t)v * 8 + q];    // self-loop
    float tq[8];
#pragma unroll
    for (int j = 0; j < 8; ++j) tq[j] = __shfl(s, j, 64);
    if (lane < 32) {
        float dv = dis[v];
        float acc = 0.f;
#pragma unroll
        for (int j = 0; j < 8; ++j) acc += tq[j] * sW[j * 32 + lane];
        h[(size_t)v * 32 + lane] = fmaxf(dv * acc + b1[lane], 0.f);
    }
}

// g2[v][f] = dis[v] * sum_k h[v][k] * W2[k][f]   (in-place over h)
__global__ void k_gemm2(const float* __restrict__ W2, const float* __restrict__ dis,
                        float* __restrict__ h, int n) {
    __shared__ float sW[1024];
    __shared__ float sh[8][33];    // +1 pad: rows land in distinct banks
    int t = threadIdx.x;
    for (int i = t; i < 1024; i += 256) sW[i] = W2[i];
    int idx = blockIdx.x * 256 + t;
    int v = idx >> 5, f = t & 31, row = t >> 5;
    sh[row][f] = (v < n) ? h[idx] : 0.f;
    __syncthreads();
    if (v >= n) return;
    float s = 0.f;
#pragma unroll
    for (int k = 0; k < 32; ++k) s += sh[row][k] * sW[k * 32 + f];
    h[idx] = s * dis[v];
}

// layer 2 + head fused
__global__ void k_g2f(const int* __restrict__ rowptr, const int* __restrict__ col,
                      const float4* __restrict__ g4, const float* __restrict__ dis,
                      const float* __restrict__ b2, const float* __restrict__ Wf,
                      const float* __restrict__ bf, float* __restrict__ out, int n) {
    int t = threadIdx.x;
    int v = blockIdx.x * 4 + (t >> 6);
    if (v >= n) return;
    int lane = t & 63, slot = lane >> 3, q = lane & 7;
    int r0 = rowptr[v], r1 = rowptr[v + 1];
    float4 s = make_float4(0.f, 0.f, 0.f, 0.f);
    for (int i = r0 + slot; i < r1; i += 8) {
        float4 gv = g4[(size_t)col[i] * 8 + q];
        s.x += gv.x; s.y += gv.y; s.z += gv.z; s.w += gv.w;
    }
#pragma unroll
    for (int m = 8; m < 64; m <<= 1) {
        s.x += __shfl_xor(s.x, m, 64);
        s.y += __shfl_xor(s.y, m, 64);
        s.z += __shfl_xor(s.z, m, 64);
        s.w += __shfl_xor(s.w, m, 64);
    }
    float4 gv = g4[(size_t)v * 8 + q];
    float4 bv = ((const float4*)b2)[q];
    float4 wv = ((const float4*)Wf)[q];
    float dv = dis[v];
    float p = fmaxf(dv * (s.x + gv.x) + bv.x, 0.f) * wv.x
            + fmaxf(dv * (s.y + gv.y) + bv.y, 0.f) * wv.y
            + fmaxf(dv * (s.z + gv.z) + bv.z, 0.f) * wv.z
            + fmaxf(dv * (s.w + gv.w) + bv.w, 0.f) * wv.w;
    p += __shfl_xor(p, 1, 64);
    p += __shfl_xor(p, 2, 64);
    p += __shfl_xor(p, 4, 64);
    if (lane == 0) out[v] = p + bf[0];
}

extern "C" void kernel_launch(void* const* d_in, const int* in_sizes, int n_in,
                              void* d_out, int out_size, void* d_ws, size_t ws_size,
                              hipStream_t stream) {
    const float* x  = (const float*)d_in[0];
    const int*   ei = (const int*)d_in[1];   // [2, E] int32
    const float* W1 = (const float*)d_in[2];
    const float* b1 = (const float*)d_in[3];
    const float* W2 = (const float*)d_in[4];
    const float* b2 = (const float*)d_in[5];
    const float* Wf = (const float*)d_in[6];
    const float* bf = (const float*)d_in[7];
    float* out = (float*)d_out;

    const int n = in_sizes[0] / 8;
    const int E = in_sizes[1] / 2;
    const int* src = ei;
    const int* dst = ei + E;
    const int nbuck = (n + 255) >> 8;        // n=100k -> 391

    // workspace (~33.4 MB)
    float* dis   = (float*)d_ws;                // n
    float* xs    = dis + n;                     // 8n
    float* h     = xs + (size_t)n * 8;          // 32n (h1, then g2 in-place)
    int* rowptr  = (int*)(h + (size_t)n * 32);  // n+1
    int* bbase   = rowptr + (n + 1);            // 513
    int* part    = bbase + 513;                 // NBLK*512
    int* col     = part + NBLK * 512;           // E
    int* bpair   = col + E;                     // E

    // --- CSR build (zero global atomics) ---
    k_hist <<<dim3(NBLK), dim3(256), 0, stream>>>(dst, part, E);
    k_scan2<<<dim3(1),    dim3(512), 0, stream>>>(part, bbase, rowptr, n, E);
    k_binA2<<<dim3(NBLK), dim3(512), 0, stream>>>(src, dst, part, bbase, bpair, E);
    k_fill2<<<dim3(nbuck),dim3(512), 0, stream>>>(bpair, bbase, x, rowptr, dis, xs, col, n);

    // --- layer 1 ---
    k_g1<<<dim3((n + 3) / 4), dim3(256), 0, stream>>>(rowptr, col, xs, dis, W1, b1, h, n);
    k_gemm2<<<dim3((n * 32 + 255) / 256), dim3(256), 0, stream>>>(W2, dis, h, n);

    // --- layer 2 + head ---
    k_g2f<<<dim3((n + 3) / 4), dim3(256), 0, stream>>>(rowptr, col, (const float4*)h, dis,
                                                       b2, Wf, bf, out, n);
}

// Round 7
// 150.485 us; speedup vs baseline: 11.7842x; 1.0892x over previous
//
#include <hip/hip_runtime.h>

// ---------------------------------------------------------------------------
// RoutingGNN: 2-layer GCN (sym-norm, self-loops) + linear head.
// Round 7: k_g2f / k_g1 are latency-bound gathers (VALUBusy 34%, BW 2.1TB/s
// << ceilings). Widen MLP: 16 edge-slots x 4 lanes, 2 independent float4
// gather streams per lane (g2f) / float2 (g1). Re-fuse W2 matvec into k_g1
// via LDS split-k (NOT shuffles - round-5 lesson), killing k_gemm2 and its
// 25.6MB h round-trip.
//   CSR build (zero global atomics): k_hist -> k_scan2 -> k_binA2 -> k_fill2
//   k_g1w2 : gather8(xs) + W1 + relu + W2(LDS) -> g   (h never hits memory)
//   k_g2f  : gather32(g) + combine + relu + Wf head -> out
// ---------------------------------------------------------------------------

#define NBLK 256
#define SHIFT 8          // 256 nodes/bucket; n <= 131072 -> <= 512 buckets
#define BMASK 255

// per-block bucket histogram -> part[b][512]  (no global atomics)
__global__ void k_hist(const int* __restrict__ dst, int* __restrict__ part, int E) {
    __shared__ int hist[512];
    int t = threadIdx.x;           // 256
    hist[t] = 0; hist[t + 256] = 0;
    __syncthreads();
    int E4 = E >> 2;
    int chunk4 = (E4 + NBLK - 1) / NBLK;
    int b = blockIdx.x;
    int s4 = b * chunk4;
    int e4 = min(s4 + chunk4, E4);
    const int4* dst4 = (const int4*)dst;
    for (int i = s4 + t; i < e4; i += 256) {
        int4 d = dst4[i];
        atomicAdd(&hist[d.x >> SHIFT], 1);
        atomicAdd(&hist[d.y >> SHIFT], 1);
        atomicAdd(&hist[d.z >> SHIFT], 1);
        atomicAdd(&hist[d.w >> SHIFT], 1);
    }
    if (b == NBLK - 1) {
        for (int e = (E4 << 2) + t; e < E; e += 256)
            atomicAdd(&hist[dst[e] >> SHIFT], 1);
    }
    __syncthreads();
    part[b * 512 + t] = hist[t];
    part[b * 512 + 256 + t] = hist[t + 256];
}

// single block, 512 thr: column-walk partials -> per-block exclusive offsets;
// LDS scan of column totals -> bbase (exclusive bucket bases)
__global__ void k_scan2(int* __restrict__ part, int* __restrict__ bbase,
                        int* __restrict__ rowptr, int n, int E) {
    __shared__ int tmp[512];
    int t = threadIdx.x;
    int run = 0;
    for (int b = 0; b < NBLK; b += 4) {
        int i0 = (b + 0) * 512 + t, i1 = (b + 1) * 512 + t;
        int i2 = (b + 2) * 512 + t, i3 = (b + 3) * 512 + t;
        int c0 = part[i0], c1 = part[i1], c2 = part[i2], c3 = part[i3];
        part[i0] = run; run += c0;
        part[i1] = run; run += c1;
        part[i2] = run; run += c2;
        part[i3] = run; run += c3;
    }
    tmp[t] = run;
    __syncthreads();
    int v = run;
    for (int off = 1; off < 512; off <<= 1) {
        int add = (t >= off) ? tmp[t - off] : 0;
        __syncthreads();
        tmp[t] += add;
        __syncthreads();
    }
    bbase[t] = tmp[t] - v;
    if (t == 511) bbase[512] = tmp[511];
    if (t == 0) rowptr[n] = E;
}

// bin edges into bucket-ordered packed words via block-private LDS cursors
__global__ void k_binA2(const int* __restrict__ src, const int* __restrict__ dst,
                        const int* __restrict__ part, const int* __restrict__ bbase,
                        int* __restrict__ bpair, int E) {
    __shared__ int cur[512];
    int t = threadIdx.x;           // 512
    int b = blockIdx.x;
    cur[t] = part[b * 512 + t] + bbase[t];
    __syncthreads();
    int E4 = E >> 2;
    int chunk4 = (E4 + NBLK - 1) / NBLK;
    int s4 = b * chunk4;
    int e4 = min(s4 + chunk4, E4);
    const int4* src4 = (const int4*)src;
    const int4* dst4 = (const int4*)dst;
    for (int i = s4 + t; i < e4; i += 512) {
        int4 s = src4[i];
        int4 d = dst4[i];
        int p0 = atomicAdd(&cur[d.x >> SHIFT], 1);
        bpair[p0] = (s.x << SHIFT) | (d.x & BMASK);
        int p1 = atomicAdd(&cur[d.y >> SHIFT], 1);
        bpair[p1] = (s.y << SHIFT) | (d.y & BMASK);
        int p2 = atomicAdd(&cur[d.z >> SHIFT], 1);
        bpair[p2] = (s.z << SHIFT) | (d.z & BMASK);
        int p3 = atomicAdd(&cur[d.w >> SHIFT], 1);
        bpair[p3] = (s.w << SHIFT) | (d.w & BMASK);
    }
    if (b == NBLK - 1) {
        for (int e = (E4 << 2) + t; e < E; e += 512) {
            int sv = src[e], dv = dst[e];
            int p = atomicAdd(&cur[dv >> SHIFT], 1);
            bpair[p] = (sv << SHIFT) | (dv & BMASK);
        }
    }
}

// one block (512 thr) per bucket: LDS counting sort -> rowptr/dis/col; fused xs
__global__ void k_fill2(const int* __restrict__ bpair, const int* __restrict__ bbase,
                        const float* __restrict__ x,
                        int* __restrict__ rowptr, float* __restrict__ dis,
                        float* __restrict__ xs, int* __restrict__ col, int n) {
    __shared__ int cnt[256];
    __shared__ int tmp[256];
    __shared__ int cur[256];
    __shared__ float sdis[256];
    int b = blockIdx.x;
    int t = threadIdx.x;           // 512
    int start = bbase[b], end = bbase[b + 1];
    if (t < 256) cnt[t] = 0;
    __syncthreads();
    for (int i = start + t; i < end; i += 512)
        atomicAdd(&cnt[bpair[i] & BMASK], 1);
    __syncthreads();
    int v0 = (t < 256) ? cnt[t] : 0;
    if (t < 256) tmp[t] = v0;
    __syncthreads();
    for (int off = 1; off < 256; off <<= 1) {
        int add = (t < 256 && t >= off) ? tmp[t - off] : 0;
        __syncthreads();
        if (t < 256) tmp[t] += add;
        __syncthreads();
    }
    if (t < 256) {
        int v = (b << SHIFT) + t;
        if (v < n) {
            int r = start + tmp[t] - v0;
            rowptr[v] = r;
            cur[t] = r;
            float dv = rsqrtf(1.0f + (float)v0);
            dis[v] = dv;
            sdis[t] = dv;
        }
    }
    __syncthreads();
    int gbase = (b << SHIFT) * 8;
    int n8 = n * 8;
    for (int i = t; i < 2048; i += 512) {
        int gi = gbase + i;
        if (gi < n8) xs[gi] = x[gi] * sdis[i >> 3];
    }
    for (int i = start + t; i < end; i += 512) {
        int p = bpair[i];
        int pos = atomicAdd(&cur[p & BMASK], 1);
        col[pos] = p >> SHIFT;
    }
}

// layer 1 fused: agg8 = sum_{u->v} xs[u] (+ xs[v]);
// h = relu(dis*(agg8@W1)+b1)  (registers/LDS only);  g = dis*(h@W2)
// 16 edge-slots x 4 lanes x float2; W2 matvec via LDS split-k across halves.
__global__ void k_g1w2(const int* __restrict__ rowptr, const int* __restrict__ col,
                       const float2* __restrict__ xs2, const float* __restrict__ dis,
                       const float* __restrict__ W1, const float* __restrict__ b1,
                       const float* __restrict__ W2, float* __restrict__ g, int n) {
    __shared__ float sW1[256];
    __shared__ float sW2[1024];
    __shared__ float sh[4][32];
    int t = threadIdx.x;
    sW1[t] = W1[t];
    for (int i = t; i < 1024; i += 256) sW2[i] = W2[i];
    __syncthreads();
    int widx = t >> 6;
    int v = blockIdx.x * 4 + widx;
    if (v >= n) return;
    int lane = t & 63, slot = lane >> 2, q = lane & 3;
    int r0 = rowptr[v], r1 = rowptr[v + 1];
    float2 s = make_float2(0.f, 0.f);
    for (int i = r0 + slot; i < r1; i += 16) {
        float2 xv = xs2[(size_t)col[i] * 4 + q];
        s.x += xv.x; s.y += xv.y;
    }
#pragma unroll
    for (int m = 4; m < 64; m <<= 1) {
        s.x += __shfl_xor(s.x, m, 64);
        s.y += __shfl_xor(s.y, m, 64);
    }
    float2 xv = xs2[(size_t)v * 4 + q];   // self-loop
    s.x += xv.x; s.y += xv.y;
    float tq[8];
#pragma unroll
    for (int j = 0; j < 4; ++j) {
        tq[2 * j]     = __shfl(s.x, j, 64);
        tq[2 * j + 1] = __shfl(s.y, j, 64);
    }
    int f = lane & 31, half = lane >> 5;
    float dv = dis[v];
    float acc = 0.f;
#pragma unroll
    for (int j = 0; j < 8; ++j) acc += tq[j] * sW1[j * 32 + f];
    float hp = fmaxf(dv * acc + b1[f], 0.f);
    if (half == 0) sh[widx][f] = hp;
    // wave-internal LDS RAW: in-order within the wave (compiler emits lgkmcnt)
    float g2 = 0.f;
    int k0 = half << 4;
#pragma unroll
    for (int k = 0; k < 16; ++k) g2 += sh[widx][k0 + k] * sW2[(k0 + k) * 32 + f];
    g2 += __shfl_xor(g2, 32, 64);
    if (half == 0) g[(size_t)v * 32 + f] = g2 * dv;
}

// layer 2 + head fused: 16 edge-slots x 4 lanes, 2 float4 gather streams.
__global__ void k_g2f(const int* __restrict__ rowptr, const int* __restrict__ col,
                      const float4* __restrict__ g4, const float* __restrict__ dis,
                      const float* __restrict__ b2, const float* __restrict__ Wf,
                      const float* __restrict__ bf, float* __restrict__ out, int n) {
    int t = threadIdx.x;
    int v = blockIdx.x * 4 + (t >> 6);
    if (v >= n) return;
    int lane = t & 63, slot = lane >> 2, q = lane & 3;
    int r0 = rowptr[v], r1 = rowptr[v + 1];
    float4 s0 = make_float4(0.f, 0.f, 0.f, 0.f);
    float4 s1 = make_float4(0.f, 0.f, 0.f, 0.f);
    for (int i = r0 + slot; i < r1; i += 16) {
        size_t c8 = (size_t)col[i] * 8;
        float4 a = g4[c8 + q];
        float4 b = g4[c8 + q + 4];
        s0.x += a.x; s0.y += a.y; s0.z += a.z; s0.w += a.w;
        s1.x += b.x; s1.y += b.y; s1.z += b.z; s1.w += b.w;
    }
#pragma unroll
    for (int m = 4; m < 64; m <<= 1) {
        s0.x += __shfl_xor(s0.x, m, 64);
        s0.y += __shfl_xor(s0.y, m, 64);
        s0.z += __shfl_xor(s0.z, m, 64);
        s0.w += __shfl_xor(s0.w, m, 64);
        s1.x += __shfl_xor(s1.x, m, 64);
        s1.y += __shfl_xor(s1.y, m, 64);
        s1.z += __shfl_xor(s1.z, m, 64);
        s1.w += __shfl_xor(s1.w, m, 64);
    }
    size_t v8 = (size_t)v * 8;
    float4 a = g4[v8 + q];               // self-loop
    float4 b = g4[v8 + q + 4];
    s0.x += a.x; s0.y += a.y; s0.z += a.z; s0.w += a.w;
    s1.x += b.x; s1.y += b.y; s1.z += b.z; s1.w += b.w;
    float dv = dis[v];
    float4 bv0 = ((const float4*)b2)[q], bv1 = ((const float4*)b2)[q + 4];
    float4 wv0 = ((const float4*)Wf)[q], wv1 = ((const float4*)Wf)[q + 4];
    float p = fmaxf(dv * s0.x + bv0.x, 0.f) * wv0.x
            + fmaxf(dv * s0.y + bv0.y, 0.f) * wv0.y
            + fmaxf(dv * s0.z + bv0.z, 0.f) * wv0.z
            + fmaxf(dv * s0.w + bv0.w, 0.f) * wv0.w
            + fmaxf(dv * s1.x + bv1.x, 0.f) * wv1.x
            + fmaxf(dv * s1.y + bv1.y, 0.f) * wv1.y
            + fmaxf(dv * s1.z + bv1.z, 0.f) * wv1.z
            + fmaxf(dv * s1.w + bv1.w, 0.f) * wv1.w;
    p += __shfl_xor(p, 1, 64);
    p += __shfl_xor(p, 2, 64);
    if (lane == 0) out[v] = p + bf[0];
}

extern "C" void kernel_launch(void* const* d_in, const int* in_sizes, int n_in,
                              void* d_out, int out_size, void* d_ws, size_t ws_size,
                              hipStream_t stream) {
    const float* x  = (const float*)d_in[0];
    const int*   ei = (const int*)d_in[1];   // [2, E] int32
    const float* W1 = (const float*)d_in[2];
    const float* b1 = (const float*)d_in[3];
    const float* W2 = (const float*)d_in[4];
    const float* b2 = (const float*)d_in[5];
    const float* Wf = (const float*)d_in[6];
    const float* bf = (const float*)d_in[7];
    float* out = (float*)d_out;

    const int n = in_sizes[0] / 8;
    const int E = in_sizes[1] / 2;
    const int* src = ei;
    const int* dst = ei + E;
    const int nbuck = (n + 255) >> 8;        // n=100k -> 391

    // workspace (~33.4 MB)
    float* dis   = (float*)d_ws;                // n
    float* xs    = dis + n;                     // 8n
    float* g     = xs + (size_t)n * 8;          // 32n
    int* rowptr  = (int*)(g + (size_t)n * 32);  // n+1
    int* bbase   = rowptr + (n + 1);            // 513
    int* part    = bbase + 513;                 // NBLK*512
    int* col     = part + NBLK * 512;           // E
    int* bpair   = col + E;                     // E

    // --- CSR build (zero global atomics) ---
    k_hist <<<dim3(NBLK), dim3(256), 0, stream>>>(dst, part, E);
    k_scan2<<<dim3(1),    dim3(512), 0, stream>>>(part, bbase, rowptr, n, E);
    k_binA2<<<dim3(NBLK), dim3(512), 0, stream>>>(src, dst, part, bbase, bpair, E);
    k_fill2<<<dim3(nbuck),dim3(512), 0, stream>>>(bpair, bbase, x, rowptr, dis, xs, col, n);

    // --- layer 1 (gather8 + W1 + relu + W2, LDS-fused) ---
    k_g1w2<<<dim3((n + 3) / 4), dim3(256), 0, stream>>>(rowptr, col, (const float2*)xs,
                                                        dis, W1, b1, W2, g, n);

    // --- layer 2 + head ---
    k_g2f<<<dim3((n + 3) / 4), dim3(256), 0, stream>>>(rowptr, col, (const float4*)g, dis,
                                                       b2, Wf, bf, out, n);
}